// Round 1
// baseline (1409.817 us; speedup 1.0000x reference)
//
#include <hip/hip_runtime.h>
#include <hip/hip_bf16.h>

#define MTOT 8192              // B*T
#define TLEN 4096              // T
#define CDIM 2048              // C
#define SLOT ((size_t)MTOT * CDIM)   // elements per output tensor

typedef __attribute__((ext_vector_type(4))) float f32x4;
typedef __attribute__((ext_vector_type(8))) __bf16 bf16x8;

__device__ __forceinline__ short f2bf(float f) {
  __hip_bfloat16 h = __float2bfloat16(f);
  return __builtin_bit_cast(short, h);
}

__device__ __forceinline__ float sigm(float x) { return 1.f / (1.f + expf(-x)); }

// async global->LDS, 16B per lane; LDS dest = wave-uniform base + lane*16
__device__ __forceinline__ void gload16(const void* g, void* l) {
  __builtin_amdgcn_global_load_lds(
      (__attribute__((address_space(1))) void*)g,
      (__attribute__((address_space(3))) void*)l, 16, 0, 0);
}

// ---------------------------------------------------------------------------
// Core 128x128 tile GEMM (NT): C[m,n] = sum_k A[m,k] * Bt[n,k]
// block = 256 threads (4 waves), BK=32, 16x16x32 bf16 MFMA, 4x4 acc per wave
// ---------------------------------------------------------------------------
__device__ __forceinline__ void gemm_core(
    const short* __restrict__ A, int lda,
    const short* __restrict__ Bt, int ldb,
    int K, int m0, int n0,
    short* As, short* Bs, f32x4 acc[4][4])
{
  const int tid  = threadIdx.x;
  const int lane = tid & 63;
  const int wv   = tid >> 6;        // wave 0..3
  const int wy   = wv >> 1;
  const int wx   = wv & 1;
  const int quad = lane >> 4;
  const int m16  = lane & 15;

  const f32x4 zero = {0.f, 0.f, 0.f, 0.f};
  #pragma unroll
  for (int i = 0; i < 4; ++i)
    #pragma unroll
    for (int j = 0; j < 4; ++j)
      acc[i][j] = zero;

  // staging geometry: tile = 128 rows x 32 cols bf16 (8 KB). Two chunks per wave.
  const int e0 = (wv * 64 + lane) * 8;   // element offset of chunk 0
  const int e1 = e0 + 2048;              // chunk 1
  const int r0 = e0 >> 5, c0 = e0 & 31;
  const int r1 = e1 >> 5, c1 = e1 & 31;
  const int lb0 = wv * 512;              // LDS base (elems), wave-uniform
  const int lb1 = 2048 + wv * 512;

  const short* pa0 = A  + (size_t)(m0 + r0) * lda + c0;
  const short* pa1 = A  + (size_t)(m0 + r1) * lda + c1;
  const short* pb0 = Bt + (size_t)(n0 + r0) * ldb + c0;
  const short* pb1 = Bt + (size_t)(n0 + r1) * ldb + c1;

  for (int k0 = 0; k0 < K; k0 += 32) {
    gload16(pa0 + k0, As + lb0);
    gload16(pa1 + k0, As + lb1);
    gload16(pb0 + k0, Bs + lb0);
    gload16(pb1 + k0, Bs + lb1);
    __syncthreads();

    bf16x8 af[4], bfr[4];
    #pragma unroll
    for (int mi = 0; mi < 4; ++mi)
      af[mi] = *(const bf16x8*)(As + (wy*64 + mi*16 + m16)*32 + quad*8);
    #pragma unroll
    for (int ni = 0; ni < 4; ++ni)
      bfr[ni] = *(const bf16x8*)(Bs + (wx*64 + ni*16 + m16)*32 + quad*8);

    #pragma unroll
    for (int mi = 0; mi < 4; ++mi)
      #pragma unroll
      for (int ni = 0; ni < 4; ++ni)
        acc[mi][ni] = __builtin_amdgcn_mfma_f32_16x16x32_bf16(
            af[mi], bfr[ni], acc[mi][ni], 0, 0, 0);
    __syncthreads();
  }
}

// ---------------------------------------------------------------------------
// Elementwise mix: xx = xprev - x; out_j = bf16(x + xx*coef_j); also v_first copy
// ---------------------------------------------------------------------------
__global__ __launch_bounds__(256) void mix_kernel(
    const float* __restrict__ x, const float* __restrict__ vfin,
    const float* __restrict__ cr, const float* __restrict__ cw,
    const float* __restrict__ ck, const float* __restrict__ cv,
    const float* __restrict__ ca, const float* __restrict__ cg,
    short* __restrict__ xr, short* __restrict__ xw, short* __restrict__ xk,
    short* __restrict__ xv, short* __restrict__ xa, short* __restrict__ xg,
    float* __restrict__ vfout)
{
  const size_t i = (size_t)blockIdx.x * 256 + threadIdx.x;  // over MTOT*CDIM/4
  const size_t e = i * 4;
  const int c = (int)(e & (CDIM - 1));
  const size_t m = e >> 11;            // / CDIM
  const int t = (int)(m & (TLEN - 1));
  const float4 xc = *(const float4*)(x + e);
  float4 xp = make_float4(0.f, 0.f, 0.f, 0.f);
  if (t > 0) xp = *(const float4*)(x + e - CDIM);
  const float d0 = xp.x - xc.x, d1 = xp.y - xc.y;
  const float d2 = xp.z - xc.z, d3 = xp.w - xc.w;

  *(float4*)(vfout + e) = *(const float4*)(vfin + e);

  #define EMIT(coef, dst) { \
    const float4 cf = *(const float4*)((coef) + c); \
    short4 s; \
    s.x = f2bf(xc.x + d0 * cf.x); \
    s.y = f2bf(xc.y + d1 * cf.y); \
    s.z = f2bf(xc.z + d2 * cf.z); \
    s.w = f2bf(xc.w + d3 * cf.w); \
    *(short4*)((dst) + e) = s; }
  EMIT(cr, xr) EMIT(cw, xw) EMIT(ck, xk) EMIT(cv, xv) EMIT(ca, xa) EMIT(cg, xg)
  #undef EMIT
}

// fp32 -> bf16 straight convert for Wr/Wk/Wv
__global__ __launch_bounds__(256) void cvt_big(
    const float* __restrict__ Wr, const float* __restrict__ Wk,
    const float* __restrict__ Wv,
    short* __restrict__ br, short* __restrict__ bk, short* __restrict__ bv)
{
  const int z = blockIdx.y;
  const float* src = (z == 0) ? Wr : (z == 1) ? Wk : Wv;
  short* dst = (z == 0) ? br : (z == 1) ? bk : bv;
  const size_t e = ((size_t)blockIdx.x * 256 + threadIdx.x) * 4;  // over CDIM*CDIM
  const float4 v = *(const float4*)(src + e);
  short4 s;
  s.x = f2bf(v.x); s.y = f2bf(v.y); s.z = f2bf(v.z); s.w = f2bf(v.w);
  *(short4*)(dst + e) = s;
}

// transpose (+zero-pad) small weights into bf16 [N,K] ("B^T") layout
__global__ __launch_bounds__(256) void wtrans(
    const float* __restrict__ w1, const float* __restrict__ a1,
    const float* __restrict__ v1, const float* __restrict__ g1,
    const float* __restrict__ w2, const float* __restrict__ a2,
    const float* __restrict__ v2, const float* __restrict__ g2,
    short* __restrict__ w1t, short* __restrict__ a1t,
    short* __restrict__ v1t, short* __restrict__ g1t,
    short* __restrict__ w2t, short* __restrict__ a2t,
    short* __restrict__ v2t, short* __restrict__ g2t)
{
  const int task = blockIdx.y;
  const int i = blockIdx.x * 256 + threadIdx.x;
  switch (task) {
    case 0: if (i < 128*2048) { int d=i>>11, c=i&2047; w1t[i]=f2bf(w1[(size_t)c*128+d]); } break;
    case 1: if (i < 128*2048) { int d=i>>11, c=i&2047; a1t[i]=f2bf(a1[(size_t)c*128+d]); } break;
    case 2: if (i < 128*2048) { int d=i>>11, c=i&2047; v1t[i]=(d<64)?f2bf(v1[(size_t)c*64+d]):(short)0; } break;
    case 3: if (i < 256*2048) { int d=i>>11, c=i&2047; g1t[i]=(d<224)?f2bf(g1[(size_t)c*224+d]):(short)0; } break;
    case 4: if (i < 2048*128) { int c=i>>7, d=i&127; w2t[i]=f2bf(w2[(size_t)d*2048+c]); } break;
    case 5: if (i < 2048*128) { int c=i>>7, d=i&127; a2t[i]=f2bf(a2[(size_t)d*2048+c]); } break;
    case 6: if (i < 2048*64)  { int c=i>>6, d=i&63;  v2t[i]=f2bf(v2[(size_t)d*2048+c]); } break;
    case 7: if (i < 2048*224) { int c=i/224, d=i-c*224; g2t[i]=f2bf(g2[(size_t)d*2048+c]); } break;
  }
}

// big projections: r = xr@Wr^T -> slot0 ; kraw = xk@Wk^T -> slot2 ; vraw = xv@Wv^T -> slot3
__global__ __launch_bounds__(256) void gemm_big(
    const short* __restrict__ xr, const short* __restrict__ xk,
    const short* __restrict__ xv,
    const short* __restrict__ Wr, const short* __restrict__ Wk,
    const short* __restrict__ Wv,
    float* __restrict__ out)
{
  __shared__ short As[4096], Bs[4096];
  const int z = blockIdx.z;
  const short* A  = (z == 0) ? xr : (z == 1) ? xk : xv;
  const short* Bt = (z == 0) ? Wr : (z == 1) ? Wk : Wv;
  float* O = (z == 0) ? out : (z == 1) ? out + 2*SLOT : out + 3*SLOT;
  const int m0 = blockIdx.x * 128, n0 = blockIdx.y * 128;
  f32x4 acc[4][4];
  gemm_core(A, CDIM, Bt, CDIM, CDIM, m0, n0, As, Bs, acc);

  const int tid=threadIdx.x, lane=tid&63, wv=tid>>6;
  const int wy=wv>>1, wx=wv&1, quad=lane>>4, m16=lane&15;
  #pragma unroll
  for (int mi = 0; mi < 4; ++mi) {
    const int mb = m0 + wy*64 + mi*16 + quad*4;
    #pragma unroll
    for (int ni = 0; ni < 4; ++ni) {
      const int n = n0 + wx*64 + ni*16 + m16;
      #pragma unroll
      for (int r = 0; r < 4; ++r)
        O[(size_t)(mb + r) * CDIM + n] = acc[mi][ni][r];
    }
  }
}

// stage-1 LoRA: h_w=tanh(xw@w1), h_a=xa@a1, h_v=xv@v1, h_g=sigmoid(xg@g1)  (bf16 out)
__global__ __launch_bounds__(256) void gemm_s1(
    const short* __restrict__ xw, const short* __restrict__ xa,
    const short* __restrict__ xv, const short* __restrict__ xg,
    const short* __restrict__ w1t, const short* __restrict__ a1t,
    const short* __restrict__ v1t, const short* __restrict__ g1t,
    short* __restrict__ hw, short* __restrict__ ha,
    short* __restrict__ hv, short* __restrict__ hg)
{
  const int z = blockIdx.z;
  const int nb = blockIdx.y;
  if (z != 3 && nb != 0) return;      // only g has 2 n-blocks
  __shared__ short As[4096], Bs[4096];
  const short* A  = (z==0) ? xw  : (z==1) ? xa  : (z==2) ? xv  : xg;
  const short* Bt = (z==0) ? w1t : (z==1) ? a1t : (z==2) ? v1t : g1t;
  short* H        = (z==0) ? hw  : (z==1) ? ha  : (z==2) ? hv  : hg;
  const int Nreal = (z==2) ? 64 : (z==3) ? 224 : 128;
  const int m0 = blockIdx.x * 128, n0 = nb * 128;
  f32x4 acc[4][4];
  gemm_core(A, CDIM, Bt, CDIM, CDIM, m0, n0, As, Bs, acc);

  const int tid=threadIdx.x, lane=tid&63, wv=tid>>6;
  const int wy=wv>>1, wx=wv&1, quad=lane>>4, m16=lane&15;
  #pragma unroll
  for (int mi = 0; mi < 4; ++mi) {
    const int mb = m0 + wy*64 + mi*16 + quad*4;
    #pragma unroll
    for (int ni = 0; ni < 4; ++ni) {
      const int n = n0 + wx*64 + ni*16 + m16;
      if (n < Nreal) {
        #pragma unroll
        for (int r = 0; r < 4; ++r) {
          float v = acc[mi][ni][r];
          if (z == 0) v = tanhf(v);
          else if (z == 3) v = sigm(v);
          H[(size_t)(mb + r) * Nreal + n] = f2bf(v);
        }
      }
    }
  }
}

// stage-2 LoRA with fused epilogues:
//  z0: w = -softplus(-(w0 + hw@w2)) - 0.5        -> slot1
//  z1: a = sigmoid(a0 + ha@a2)                   -> slot4
//  z2: v = vraw + (v_first - vraw)*sigmoid(v0 + hv@v2)   (in-place slot3)
//  z3: g = hg@g2                                 -> slot5
__global__ __launch_bounds__(256) void gemm_s2(
    const short* __restrict__ hw, const short* __restrict__ ha,
    const short* __restrict__ hv, const short* __restrict__ hg,
    const short* __restrict__ w2t, const short* __restrict__ a2t,
    const short* __restrict__ v2t, const short* __restrict__ g2t,
    const float* __restrict__ w0, const float* __restrict__ a0,
    const float* __restrict__ v0, const float* __restrict__ vfirst,
    float* __restrict__ out)
{
  __shared__ short As[4096], Bs[4096];
  const int z = blockIdx.z;
  const short* A  = (z==0) ? hw  : (z==1) ? ha  : (z==2) ? hv  : hg;
  const short* Bt = (z==0) ? w2t : (z==1) ? a2t : (z==2) ? v2t : g2t;
  const int K = (z==2) ? 64 : (z==3) ? 224 : 128;
  const int m0 = blockIdx.x * 128, n0 = blockIdx.y * 128;
  f32x4 acc[4][4];
  gemm_core(A, K, Bt, K, K, m0, n0, As, Bs, acc);

  const int tid=threadIdx.x, lane=tid&63, wv=tid>>6;
  const int wy=wv>>1, wx=wv&1, quad=lane>>4, m16=lane&15;
  #pragma unroll
  for (int mi = 0; mi < 4; ++mi) {
    const int mb = m0 + wy*64 + mi*16 + quad*4;
    #pragma unroll
    for (int ni = 0; ni < 4; ++ni) {
      const int n = n0 + wx*64 + ni*16 + m16;
      #pragma unroll
      for (int r = 0; r < 4; ++r) {
        const float val = acc[mi][ni][r];
        const size_t idx = (size_t)(mb + r) * CDIM + n;
        if (z == 0) {
          float zz = w0[n] + val;
          float sp = fmaxf(-zz, 0.f) + log1pf(expf(-fabsf(zz)));
          out[SLOT + idx] = -sp - 0.5f;
        } else if (z == 1) {
          out[4*SLOT + idx] = sigm(a0[n] + val);
        } else if (z == 2) {
          const float gate = sigm(v0[n] + val);
          const float vr = out[3*SLOT + idx];
          out[3*SLOT + idx] = vr + (vfirst[idx] - vr) * gate;
        } else {
          out[5*SLOT + idx] = val;
        }
      }
    }
  }
}

// finalize: kk = normalize_per_head(kraw*k_k); k = kraw*(1+(a-1)*k_a)
__global__ __launch_bounds__(256) void fin_k(
    const float* __restrict__ kkc, const float* __restrict__ kac,
    float* __restrict__ out)
{
  const int wid  = blockIdx.x * 4 + (threadIdx.x >> 6);  // row-head id, 0..262143
  const int lane = threadIdx.x & 63;
  const size_t m = (size_t)(wid >> 5);   // / 32 heads
  const int h = wid & 31;
  const int c = h * 64 + lane;
  const size_t idx = m * CDIM + c;
  const float kraw = out[2*SLOT + idx];
  const float a    = out[4*SLOT + idx];
  const float kkv  = kraw * kkc[c];
  float ss = kkv * kkv;
  #pragma unroll
  for (int o = 32; o >= 1; o >>= 1) ss += __shfl_xor(ss, o, 64);
  const float nrm = sqrtf(ss);
  out[6*SLOT + idx] = kkv / fmaxf(nrm, 1e-12f);
  out[2*SLOT + idx] = kraw * (1.f + (a - 1.f) * kac[c]);
}

extern "C" void kernel_launch(void* const* d_in, const int* in_sizes, int n_in,
                              void* d_out, int out_size, void* d_ws, size_t ws_size,
                              hipStream_t stream) {
  (void)in_sizes; (void)n_in; (void)out_size; (void)ws_size;
  const float* x   = (const float*)d_in[0];
  const float* vf  = (const float*)d_in[1];
  const float* x_r = (const float*)d_in[2];
  const float* x_w = (const float*)d_in[3];
  const float* x_k = (const float*)d_in[4];
  const float* x_v = (const float*)d_in[5];
  const float* x_a = (const float*)d_in[6];
  const float* x_g = (const float*)d_in[7];
  const float* w0  = (const float*)d_in[8];
  const float* w1  = (const float*)d_in[9];
  const float* w2  = (const float*)d_in[10];
  const float* a0  = (const float*)d_in[11];
  const float* a1  = (const float*)d_in[12];
  const float* a2  = (const float*)d_in[13];
  const float* v0  = (const float*)d_in[14];
  const float* v1  = (const float*)d_in[15];
  const float* v2  = (const float*)d_in[16];
  const float* g1  = (const float*)d_in[17];
  const float* g2  = (const float*)d_in[18];
  const float* k_k = (const float*)d_in[19];
  const float* k_a = (const float*)d_in[20];
  const float* Wr  = (const float*)d_in[21];
  const float* Wk  = (const float*)d_in[22];
  const float* Wv  = (const float*)d_in[23];

  float* out = (float*)d_out;

  // bf16 mixed activations live in not-yet-final output slots (w,a,g):
  // each slot is 64MB fp32; each bf16 array is 32MB. Dead before those slots
  // are written by gemm_s2 (stream-ordered after gemm_big / gemm_s1).
  short* xr_b = (short*)(out + 1*SLOT);
  short* xw_b = xr_b + SLOT;
  short* xk_b = (short*)(out + 4*SLOT);
  short* xv_b = xk_b + SLOT;
  short* xa_b = (short*)(out + 5*SLOT);
  short* xg_b = xa_b + SLOT;

  // workspace: bf16 weights + LoRA hiddens (~40 MB)
  char* wsp = (char*)d_ws;
  size_t off = 0;
  #define ALLOC(var, bytes) short* var = (short*)(wsp + off); off += (((size_t)(bytes)) + 255) & ~(size_t)255;
  ALLOC(Wr_b, (size_t)CDIM*CDIM*2)
  ALLOC(Wk_b, (size_t)CDIM*CDIM*2)
  ALLOC(Wv_b, (size_t)CDIM*CDIM*2)
  ALLOC(w1t, 128*2048*2)
  ALLOC(a1t, 128*2048*2)
  ALLOC(v1t, 128*2048*2)   // zero-padded rows 64..127
  ALLOC(g1t, 256*2048*2)   // zero-padded rows 224..255
  ALLOC(w2t, 2048*128*2)
  ALLOC(a2t, 2048*128*2)
  ALLOC(v2t, 2048*64*2)
  ALLOC(g2t, 2048*224*2)
  ALLOC(hw, (size_t)MTOT*128*2)
  ALLOC(ha, (size_t)MTOT*128*2)
  ALLOC(hv, (size_t)MTOT*64*2)
  ALLOC(hg, (size_t)MTOT*224*2)
  #undef ALLOC

  mix_kernel<<<dim3(16384), 256, 0, stream>>>(
      x, vf, x_r, x_w, x_k, x_v, x_a, x_g,
      xr_b, xw_b, xk_b, xv_b, xa_b, xg_b, out + 7*SLOT);

  cvt_big<<<dim3(4096, 3), 256, 0, stream>>>(Wr, Wk, Wv, Wr_b, Wk_b, Wv_b);

  wtrans<<<dim3(2048, 8), 256, 0, stream>>>(
      w1, a1, v1, g1, w2, a2, v2, g2,
      w1t, a1t, v1t, g1t, w2t, a2t, v2t, g2t);

  gemm_big<<<dim3(64, 16, 3), 256, 0, stream>>>(
      xr_b, xk_b, xv_b, Wr_b, Wk_b, Wv_b, out);

  gemm_s1<<<dim3(64, 2, 4), 256, 0, stream>>>(
      xw_b, xa_b, xv_b, xg_b, w1t, a1t, v1t, g1t, hw, ha, hv, hg);

  gemm_s2<<<dim3(64, 16, 4), 256, 0, stream>>>(
      hw, ha, hv, hg, w2t, a2t, v2t, g2t, w0, a0, v0, vf, out);

  fin_k<<<dim3(65536), 256, 0, stream>>>(k_k, k_a, out);
}